// Round 2
// baseline (1559.699 us; speedup 1.0000x reference)
//
#include <hip/hip_runtime.h>
#include <math.h>

#define N_DST   32768
#define N_EDGE  524288
#define LN_EPS  1e-5f

typedef __attribute__((ext_vector_type(8))) short short8b;   // 8 bf16 (4 VGPR)
typedef __attribute__((ext_vector_type(4))) short short4b;   // 4 bf16 (8 B)
typedef __attribute__((ext_vector_type(4))) float f32x4;

static __device__ __forceinline__ unsigned short f2bf(float f) {
    unsigned u = __float_as_uint(f);
    u += 0x7fff + ((u >> 16) & 1);          // round-to-nearest-even
    return (unsigned short)(u >> 16);
}
static __device__ __forceinline__ float bf2f(unsigned short s) {
    return __uint_as_float(((unsigned)s) << 16);
}

// ---------- prep: pack V-weights into MFMA B-fragment order (bf16), fold zq ----------
// Wvp flat index: ((kc*7 + n)*64 + lane)*8 + jj ; value = wkv_w[100 + n*16+(lane&15)][kc*32 + (lane>>4)*8 + jj]
__global__ void k_prep(const float* __restrict__ wkv_w, const float* __restrict__ wq_w,
                       const float* __restrict__ wq_b, const float* __restrict__ time_b,
                       unsigned short* __restrict__ Wvp, float* __restrict__ zq) {
    int idx = blockIdx.x * 256 + threadIdx.x;
    if (idx < 35840) {
        int jj = idx & 7, l = (idx >> 3) & 63, n = (idx >> 9) % 7, kc = idx / 3584;
        int c = n * 16 + (l & 15);
        int k = kc * 32 + ((l >> 4) << 3) + jj;
        float v = (c < 100 && k < 300) ? wkv_w[(size_t)(100 + c) * 300 + k] : 0.f;
        Wvp[idx] = f2bf(v);
    } else if (idx < 35940) {
        int o = idx - 35840;
        float acc = wq_b[o];
        for (int j = 0; j < 100; ++j)
            acc += cosf(time_b[j]) * wq_w[o * 200 + 100 + j];
        zq[o] = acc;
    }
}

// ---------- CSR offsets via binary search over sorted edge_dst ----------
__global__ void k_offsets(const int* __restrict__ dst, int* __restrict__ off) {
    int n = blockIdx.x * 256 + threadIdx.x;
    if (n > N_DST) return;
    int lo = 0, hi = N_EDGE;
    while (lo < hi) {
        int mid = (lo + hi) >> 1;
        if (dst[mid] < n) lo = mid + 1; else hi = mid;
    }
    off[n] = lo;
}

// ---------- QW[n][h*300+k] = sum_d Q[n][h*50+d] * wkv_w[h*50+d][k] (all fp32) ----------
__global__ __launch_bounds__(256) void k_qw(const float* __restrict__ dst_h,
                                            const float* __restrict__ wq_w,
                                            const float* __restrict__ wkv_w,
                                            const float* __restrict__ zq,
                                            float* __restrict__ QW) {
    __shared__ float Ds[8][100];
    __shared__ float Qs[8][100];
    int n0 = blockIdx.x * 8, t = threadIdx.x;
    for (int idx = t; idx < 800; idx += 256)
        Ds[idx / 100][idx % 100] = dst_h[(size_t)(n0 + idx / 100) * 100 + idx % 100];
    __syncthreads();
    for (int idx = t; idx < 800; idx += 256) {
        int n = idx / 100, o = idx % 100;
        float acc = zq[o];
        const float* __restrict__ wr = wq_w + o * 200;
        #pragma unroll 4
        for (int i = 0; i < 100; ++i) acc = fmaf(Ds[n][i], wr[i], acc);
        Qs[n][o] = acc;
    }
    __syncthreads();
    for (int idx = t; idx < 4800; idx += 256) {
        int n = idx / 600, rem = idx % 600, h = rem / 300, k = rem % 300;
        float acc = 0.f;
        const float* __restrict__ qrow = &Qs[n][h * 50];
        const float* __restrict__ wcol = wkv_w + (size_t)(h * 50) * 300 + k;
        #pragma unroll 10
        for (int d = 0; d < 50; ++d) acc = fmaf(qrow[d], wcol[(size_t)d * 300], acc);
        QW[(size_t)(n0 + n) * 600 + rem] = acc;
    }
}

// ---------- edge kernel: fused staging + fp32 logits + bf16 MFMA V-GEMM ----------
// 64 edges/block, 256 thr (4 waves). X in LDS bf16 [64][320], XOR-swizzled.
// W chunks live in registers, prefetched one chunk ahead (pre-packed frag order).
__global__ __launch_bounds__(256, 4) void k_edge(
        const float* __restrict__ src_h, const float* __restrict__ efeat,
        const float* __restrict__ td,    const int* __restrict__ edge_dst,
        const float* __restrict__ time_w, const float* __restrict__ time_b,
        const unsigned short* __restrict__ Wvp, const float* __restrict__ wkv_b,
        const float* __restrict__ QW,
        unsigned short* __restrict__ Vb, float* __restrict__ attn) {
    __shared__ alignas(16) char Xs[64 * 640];   // 40 KiB: bf16 [64][320], byte(row,k)=(row*640+2k)^((row&7)<<4)
    const int t = threadIdx.x;
    const int e0 = blockIdx.x * 64;
    const int lane = t & 63;

    // prefetch W chunk 0 (coalesced 16B/lane, L2/L3-resident)
    short8b w0[7], w1[7];
    #pragma unroll
    for (int n = 0; n < 7; ++n)
        w0[n] = ((const short8b*)Wvp)[n * 64 + lane];

    // ---- staging + fp32 logits: 4 threads per edge ----
    {
        const int e = t >> 2, s = t & 3;
        const int eg = e0 + e;
        const int dst = edge_dst[eg];
        const float tdv = td[eg];
        const float* __restrict__ qwb = QW + (size_t)dst * 600;
        const float4* __restrict__ s4 = (const float4*)(src_h + (size_t)eg * 100);
        const float4* __restrict__ f4 = (const float4*)(efeat + (size_t)eg * 100);
        float p0 = 0.f, p1 = 0.f;
        #pragma unroll
        for (int j = 0; j < 20; ++j) {
            int q = s + 4 * j;                       // q in [0,80): k = 4q
            float4 x = make_float4(0.f, 0.f, 0.f, 0.f);
            if (q < 25) {
                x = s4[q];
            } else if (q < 50) {
                x = f4[q - 25];
            } else if (q < 75) {
                float4 tw = ((const float4*)time_w)[q - 50];
                float4 tb = ((const float4*)time_b)[q - 50];
                x.x = cosf(fmaf(tdv, tw.x, tb.x));
                x.y = cosf(fmaf(tdv, tw.y, tb.y));
                x.z = cosf(fmaf(tdv, tw.z, tb.z));
                x.w = cosf(fmaf(tdv, tw.w, tb.w));
            }
            if (q < 75) {
                float4 a0 = ((const float4*)qwb)[q];
                float4 a1 = ((const float4*)(qwb + 300))[q];
                p0 = fmaf(x.x, a0.x, fmaf(x.y, a0.y, fmaf(x.z, a0.z, fmaf(x.w, a0.w, p0))));
                p1 = fmaf(x.x, a1.x, fmaf(x.y, a1.y, fmaf(x.z, a1.z, fmaf(x.w, a1.w, p1))));
            }
            short4b pk;
            pk[0] = (short)f2bf(x.x); pk[1] = (short)f2bf(x.y);
            pk[2] = (short)f2bf(x.z); pk[3] = (short)f2bf(x.w);
            int wb = (e * 640 + q * 8) ^ ((e & 7) << 4);
            *(short4b*)(&Xs[wb]) = pk;
        }
        p0 += __shfl_xor(p0, 1); p0 += __shfl_xor(p0, 2);
        p1 += __shfl_xor(p1, 1); p1 += __shfl_xor(p1, 2);
        if (s == 0) {
            float l0 = p0 > 0.f ? p0 : 0.2f * p0;
            float l1 = p1 > 0.f ? p1 : 0.2f * p1;
            attn[(size_t)eg * 2]     = l0;
            attn[(size_t)eg * 2 + 1] = l1;
        }
    }
    __syncthreads();

    // ---- MFMA V-GEMM: wave wv owns Mfrag wv (16 edges) x 7 Nfrags ----
    const int wv = t >> 6;
    const int arow = wv * 16 + (lane & 15);
    const int abase = arow * 640 + ((lane >> 4) << 4);
    const int aswz = (arow & 7) << 4;
    const int col = lane & 15;

    f32x4 acc[7];
    #pragma unroll
    for (int n = 0; n < 7; ++n) {
        int cl = n * 16 + col;
        float b = (cl < 100) ? wkv_b[100 + cl] : 0.f;
        acc[n] = (f32x4){b, b, b, b};
    }
    #pragma unroll
    for (int kc = 0; kc < 10; ++kc) {
        short8b* cur = (kc & 1) ? w1 : w0;
        short8b* nxt = (kc & 1) ? w0 : w1;
        if (kc < 9) {
            #pragma unroll
            for (int n = 0; n < 7; ++n)
                nxt[n] = ((const short8b*)Wvp)[((kc + 1) * 7 + n) * 64 + lane];
        }
        short8b a = *(const short8b*)(&Xs[(abase + kc * 64) ^ aswz]);
        #pragma unroll
        for (int n = 0; n < 7; ++n)
            acc[n] = __builtin_amdgcn_mfma_f32_16x16x32_bf16(a, cur[n], acc[n], 0, 0, 0);
    }
    // V writeout (bf16): C/D layout col=lane&15, row=(lane>>4)*4+r  [m89-verified]
    const int re = e0 + wv * 16 + ((lane >> 4) << 2);
    #pragma unroll
    for (int n = 0; n < 7; ++n) {
        int cl = n * 16 + col;
        if (cl < 100) {
            #pragma unroll
            for (int r = 0; r < 4; ++r)
                Vb[(size_t)(re + r) * 100 + cl] = f2bf(acc[n][r]);
        }
    }
}

// ---------- segment softmax + weighted V reduce (V bf16, exp stored in-place) ----------
__global__ __launch_bounds__(128) void k_soft(float* __restrict__ attn,
                                              const unsigned short* __restrict__ V,
                                              const int* __restrict__ off,
                                              float* __restrict__ agg) {
    int n = blockIdx.x, t = threadIdx.x;
    int r0 = off[n], cnt = off[n + 1] - r0;
    __shared__ float red0[128], red1[128], p0s[128], p1s[128];
    if (cnt <= 0) { if (t < 100) agg[(size_t)n * 100 + t] = 0.f; return; }

    float m0 = -1e30f, m1 = -1e30f;
    for (int i = t; i < cnt; i += 128) {
        m0 = fmaxf(m0, attn[(size_t)(r0 + i) * 2]);
        m1 = fmaxf(m1, attn[(size_t)(r0 + i) * 2 + 1]);
    }
    red0[t] = m0; red1[t] = m1; __syncthreads();
    for (int s = 64; s > 0; s >>= 1) {
        if (t < s) { red0[t] = fmaxf(red0[t], red0[t + s]); red1[t] = fmaxf(red1[t], red1[t + s]); }
        __syncthreads();
    }
    m0 = red0[0]; m1 = red1[0]; __syncthreads();

    float s0 = 0.f, s1 = 0.f;
    for (int i = t; i < cnt; i += 128) {
        float e0 = expf(attn[(size_t)(r0 + i) * 2]     - m0);
        float e1 = expf(attn[(size_t)(r0 + i) * 2 + 1] - m1);
        attn[(size_t)(r0 + i) * 2]     = e0;      // overwrite logits with exp (same thread re-reads)
        attn[(size_t)(r0 + i) * 2 + 1] = e1;
        s0 += e0; s1 += e1;
    }
    red0[t] = s0; red1[t] = s1; __syncthreads();
    for (int s = 64; s > 0; s >>= 1) {
        if (t < s) { red0[t] += red0[t + s]; red1[t] += red1[t + s]; }
        __syncthreads();
    }
    float inv0 = 1.f / red0[0], inv1 = 1.f / red1[0];
    __syncthreads();

    float acc = 0.f;
    for (int base = 0; base < cnt; base += 128) {
        __syncthreads();
        int i = base + t;
        if (i < cnt) {
            p0s[t] = attn[(size_t)(r0 + i) * 2]     * inv0;
            p1s[t] = attn[(size_t)(r0 + i) * 2 + 1] * inv1;
        }
        __syncthreads();
        int lim = min(128, cnt - base);
        if (t < 100) {
            const float* pp = (t < 50) ? p0s : p1s;
            const unsigned short* __restrict__ vb = V + (size_t)(r0 + base) * 100 + t;
            for (int j = 0; j < lim; ++j)
                acc = fmaf(pp[j], bf2f(vb[(size_t)j * 100]), acc);
        }
    }
    if (t < 100) agg[(size_t)n * 100 + t] = acc;
}

// ---------- out proj + relu + layernorm ----------
__global__ __launch_bounds__(128) void k_out(const float* __restrict__ agg,
                                             const float* __restrict__ dst_h,
                                             const float* __restrict__ wout_w,
                                             const float* __restrict__ wout_b,
                                             const float* __restrict__ ln_g,
                                             const float* __restrict__ ln_b,
                                             float* __restrict__ out) {
    int n = blockIdx.x, t = threadIdx.x;
    __shared__ float al[100], dl[100], red[128];
    if (t < 100) { al[t] = agg[(size_t)n * 100 + t]; dl[t] = dst_h[(size_t)n * 100 + t]; }
    __syncthreads();
    float v = 0.f;
    if (t < 100) {
        float acc = wout_b[t];
        const float* __restrict__ wr = wout_w + t * 200;
        #pragma unroll 4
        for (int i = 0; i < 100; ++i) acc = fmaf(al[i], wr[i], acc);
        #pragma unroll 4
        for (int i = 0; i < 100; ++i) acc = fmaf(dl[i], wr[100 + i], acc);
        v = fmaxf(acc, 0.f);
    }
    red[t] = (t < 100) ? v : 0.f; __syncthreads();
    for (int s = 64; s > 0; s >>= 1) { if (t < s) red[t] += red[t + s]; __syncthreads(); }
    float mu = red[0] * 0.01f; __syncthreads();
    float dv = (t < 100) ? (v - mu) : 0.f;
    red[t] = dv * dv; __syncthreads();
    for (int s = 64; s > 0; s >>= 1) { if (t < s) red[t] += red[t + s]; __syncthreads(); }
    float var = red[0] * 0.01f;
    if (t < 100)
        out[(size_t)n * 100 + t] = (v - mu) * rsqrtf(var + LN_EPS) * ln_g[t] + ln_b[t];
}

extern "C" void kernel_launch(void* const* d_in, const int* in_sizes, int n_in,
                              void* d_out, int out_size, void* d_ws, size_t ws_size,
                              hipStream_t stream) {
    const float* dst_h   = (const float*)d_in[0];
    const float* src_h   = (const float*)d_in[1];
    const float* efeat   = (const float*)d_in[2];
    const float* td      = (const float*)d_in[3];
    const int*   edst    = (const int*)  d_in[4];
    const float* time_w  = (const float*)d_in[5];
    const float* time_b  = (const float*)d_in[6];
    const float* wq_w    = (const float*)d_in[7];
    const float* wq_b    = (const float*)d_in[8];
    const float* wkv_w   = (const float*)d_in[9];
    const float* wkv_b   = (const float*)d_in[10];
    const float* wout_w  = (const float*)d_in[11];
    const float* wout_b  = (const float*)d_in[12];
    const float* ln_g    = (const float*)d_in[13];
    const float* ln_b    = (const float*)d_in[14];
    float* out = (float*)d_out;

    char* ws = (char*)d_ws;
    size_t off = 0;
    auto carve = [&](size_t bytes) { char* p = ws + off; off = (off + bytes + 255) & ~(size_t)255; return p; };
    float*          QW   = (float*)carve((size_t)N_DST * 600 * 4);
    float*          attn = (float*)carve((size_t)N_EDGE * 2 * 4);
    unsigned short* Vb   = (unsigned short*)carve((size_t)N_EDGE * 100 * 2);
    float*          agg  = (float*)carve((size_t)N_DST * 100 * 4);
    unsigned short* Wvp  = (unsigned short*)carve(35840 * 2);
    float*          zq   = (float*)carve(100 * 4);
    int*            offs = (int*)carve((size_t)(N_DST + 1) * 4);

    k_prep<<<(35940 + 255) / 256, 256, 0, stream>>>(wkv_w, wq_w, wq_b, time_b, Wvp, zq);
    k_offsets<<<(N_DST + 1 + 255) / 256, 256, 0, stream>>>(edst, offs);
    k_qw<<<N_DST / 8, 256, 0, stream>>>(dst_h, wq_w, wkv_w, zq, QW);
    k_edge<<<N_EDGE / 64, 256, 0, stream>>>(src_h, efeat, td, edst, time_w, time_b,
                                            Wvp, wkv_b, QW, Vb, attn);
    k_soft<<<N_DST, 128, 0, stream>>>(attn, Vb, offs, agg);
    k_out<<<N_DST, 128, 0, stream>>>(agg, dst_h, wout_w, wout_b, ln_g, ln_b, out);
}

// Round 3
// 914.586 us; speedup vs baseline: 1.7054x; 1.7054x over previous
//
#include <hip/hip_runtime.h>
#include <math.h>

#define N_DST   32768
#define N_EDGE  524288
#define LN_EPS  1e-5f

typedef __attribute__((ext_vector_type(8))) short short8b;   // 8 bf16 (4 VGPR)
typedef __attribute__((ext_vector_type(4))) short short4b;   // 4 bf16 (8 B)
typedef __attribute__((ext_vector_type(4))) float f32x4;

static __device__ __forceinline__ unsigned short f2bf(float f) {
    unsigned u = __float_as_uint(f);
    u += 0x7fff + ((u >> 16) & 1);          // round-to-nearest-even
    return (unsigned short)(u >> 16);
}
static __device__ __forceinline__ float bf2f(unsigned short s) {
    return __uint_as_float(((unsigned)s) << 16);
}

// ---------- prep: pack V-weights into MFMA B-fragment order (bf16), fold zq ----------
// Wvp flat index: ((kc*7 + n)*64 + lane)*8 + jj ; value = wkv_w[100 + n*16+(lane&15)][kc*32 + (lane>>4)*8 + jj]
__global__ void k_prep(const float* __restrict__ wkv_w, const float* __restrict__ wq_w,
                       const float* __restrict__ wq_b, const float* __restrict__ time_b,
                       unsigned short* __restrict__ Wvp, float* __restrict__ zq) {
    int idx = blockIdx.x * 256 + threadIdx.x;
    if (idx < 35840) {
        int jj = idx & 7, l = (idx >> 3) & 63, n = (idx >> 9) % 7, kc = idx / 3584;
        int c = n * 16 + (l & 15);
        int k = kc * 32 + ((l >> 4) << 3) + jj;
        float v = (c < 100 && k < 300) ? wkv_w[(size_t)(100 + c) * 300 + k] : 0.f;
        Wvp[idx] = f2bf(v);
    } else if (idx < 35940) {
        int o = idx - 35840;
        float acc = wq_b[o];
        for (int j = 0; j < 100; ++j)
            acc += cosf(time_b[j]) * wq_w[o * 200 + 100 + j];
        zq[o] = acc;
    }
}

// ---------- A[i][j] = sum_d wq_w[h*50+d][i] * wkv_w[h*50+d][j%300]  (j = h*300+kk) ----------
// C[j]    = sum_d zq[h*50+d] * wkv_w[h*50+d][kk]
__global__ void k_precomp(const float* __restrict__ wq_w, const float* __restrict__ wkv_w,
                          const float* __restrict__ zq,
                          float* __restrict__ A, float* __restrict__ C) {
    int idx = blockIdx.x * 256 + threadIdx.x;
    if (idx < 60000) {
        int i = idx / 600, j = idx % 600;
        int h = j / 300, kk = j % 300;
        const float* __restrict__ wq = wq_w + (size_t)(h * 50) * 200 + i;
        const float* __restrict__ wk = wkv_w + (size_t)(h * 50) * 300 + kk;
        float acc = 0.f;
        #pragma unroll 10
        for (int d = 0; d < 50; ++d) acc = fmaf(wq[(size_t)d * 200], wk[(size_t)d * 300], acc);
        A[idx] = acc;
    } else if (idx < 60600) {
        int j = idx - 60000;
        int h = j / 300, kk = j % 300;
        float acc = 0.f;
        for (int d = 0; d < 50; ++d)
            acc = fmaf(zq[h * 50 + d], wkv_w[(size_t)(h * 50 + d) * 300 + kk], acc);
        C[j] = acc;
    }
}

// ---------- CSR offsets via binary search over sorted edge_dst ----------
__global__ void k_offsets(const int* __restrict__ dst, int* __restrict__ off) {
    int n = blockIdx.x * 256 + threadIdx.x;
    if (n > N_DST) return;
    int lo = 0, hi = N_EDGE;
    while (lo < hi) {
        int mid = (lo + hi) >> 1;
        if (dst[mid] < n) lo = mid + 1; else hi = mid;
    }
    off[n] = lo;
}

// ---------- QW = dst_h @ A + C : [32768 x 100] x [100 x 600] ----------
__global__ __launch_bounds__(256) void k_qw(const float* __restrict__ dst_h,
                                            const float* __restrict__ A,
                                            const float* __restrict__ C,
                                            float* __restrict__ QW) {
    __shared__ float Ds[16][100];
    int n0 = blockIdx.x * 16, t = threadIdx.x;
    for (int idx = t; idx < 1600; idx += 256)
        Ds[idx / 100][idx % 100] = dst_h[(size_t)n0 * 100 + idx];
    __syncthreads();
    for (int pass = 0; pass < 3; ++pass) {
        int c = pass * 256 + t;
        if (c >= 600) break;
        float cb = C[c];
        float acc[16];
        #pragma unroll
        for (int n = 0; n < 16; ++n) acc[n] = cb;
        for (int k = 0; k < 100; ++k) {
            float a = A[(size_t)k * 600 + c];
            #pragma unroll
            for (int n = 0; n < 16; ++n) acc[n] = fmaf(Ds[n][k], a, acc[n]);
        }
        #pragma unroll
        for (int n = 0; n < 16; ++n) QW[(size_t)(n0 + n) * 600 + c] = acc[n];
    }
}

// ---------- edge kernel: fused staging + fp32 logits + bf16 MFMA V-GEMM ----------
// 64 edges/block, 256 thr (4 waves). X in LDS bf16 [64][320], XOR-swizzled.
// B-fragments loaded per-kc into statically-indexed registers (NO pointer ping-pong).
__global__ __launch_bounds__(256, 4) void k_edge(
        const float* __restrict__ src_h, const float* __restrict__ efeat,
        const float* __restrict__ td,    const int* __restrict__ edge_dst,
        const float* __restrict__ time_w, const float* __restrict__ time_b,
        const unsigned short* __restrict__ Wvp, const float* __restrict__ wkv_b,
        const float* __restrict__ QW,
        unsigned short* __restrict__ Vb, float2* __restrict__ attn) {
    __shared__ alignas(16) char Xs[64 * 640];   // 40 KiB: bf16 [64][320], byte(row,k)=(row*640+2k)^((row&7)<<4)
    const int t = threadIdx.x;
    const int e0 = blockIdx.x * 64;
    const int lane = t & 63;

    // ---- staging + fp32 logits: 4 threads per edge ----
    {
        const int e = t >> 2, s = t & 3;
        const int eg = e0 + e;
        const int dst = edge_dst[eg];
        const float tdv = td[eg];
        const float* __restrict__ qwb = QW + (size_t)dst * 600;
        const float4* __restrict__ s4 = (const float4*)(src_h + (size_t)eg * 100);
        const float4* __restrict__ f4 = (const float4*)(efeat + (size_t)eg * 100);
        float p0 = 0.f, p1 = 0.f;
        #pragma unroll
        for (int j = 0; j < 20; ++j) {
            int q = s + 4 * j;                       // q in [0,80): k = 4q
            float4 x = make_float4(0.f, 0.f, 0.f, 0.f);
            if (q < 25) {
                x = s4[q];
            } else if (q < 50) {
                x = f4[q - 25];
            } else if (q < 75) {
                float4 tw = ((const float4*)time_w)[q - 50];
                float4 tb = ((const float4*)time_b)[q - 50];
                x.x = cosf(fmaf(tdv, tw.x, tb.x));
                x.y = cosf(fmaf(tdv, tw.y, tb.y));
                x.z = cosf(fmaf(tdv, tw.z, tb.z));
                x.w = cosf(fmaf(tdv, tw.w, tb.w));
            }
            if (q < 75) {
                float4 a0 = ((const float4*)qwb)[q];
                float4 a1 = ((const float4*)(qwb + 300))[q];
                p0 = fmaf(x.x, a0.x, fmaf(x.y, a0.y, fmaf(x.z, a0.z, fmaf(x.w, a0.w, p0))));
                p1 = fmaf(x.x, a1.x, fmaf(x.y, a1.y, fmaf(x.z, a1.z, fmaf(x.w, a1.w, p1))));
            }
            short4b pk;
            pk[0] = (short)f2bf(x.x); pk[1] = (short)f2bf(x.y);
            pk[2] = (short)f2bf(x.z); pk[3] = (short)f2bf(x.w);
            int wb = (e * 640 + q * 8) ^ ((e & 7) << 4);
            *(short4b*)(&Xs[wb]) = pk;
        }
        p0 += __shfl_xor(p0, 1); p0 += __shfl_xor(p0, 2);
        p1 += __shfl_xor(p1, 1); p1 += __shfl_xor(p1, 2);
        if (s == 0) {
            float l0 = p0 > 0.f ? p0 : 0.2f * p0;
            float l1 = p1 > 0.f ? p1 : 0.2f * p1;
            attn[eg] = make_float2(l0, l1);
        }
    }
    __syncthreads();

    // ---- MFMA V-GEMM: wave wv owns Mfrag wv (16 edges) x 7 Nfrags ----
    const int wv = t >> 6;
    const int col = lane & 15;
    const int arow = wv * 16 + col;
    const int abase = arow * 640 + ((lane >> 4) << 4);
    const int aswz = (arow & 7) << 4;
    const short8b* __restrict__ Wv8 = (const short8b*)Wvp;

    f32x4 acc[7];
    #pragma unroll
    for (int n = 0; n < 7; ++n) {
        int cl = n * 16 + col;
        float b = (cl < 100) ? wkv_b[100 + cl] : 0.f;
        acc[n] = (f32x4){b, b, b, b};
    }
    #pragma unroll
    for (int kc = 0; kc < 10; ++kc) {
        short8b a = *(const short8b*)(&Xs[(abase + kc * 64) ^ aswz]);
        short8b w[7];
        #pragma unroll
        for (int n = 0; n < 7; ++n)
            w[n] = Wv8[(kc * 7 + n) * 64 + lane];
        #pragma unroll
        for (int n = 0; n < 7; ++n)
            acc[n] = __builtin_amdgcn_mfma_f32_16x16x32_bf16(a, w[n], acc[n], 0, 0, 0);
    }
    // V writeout (bf16): C/D layout col=lane&15, row=(lane>>4)*4+r  [m89-verified]
    const int re = e0 + wv * 16 + ((lane >> 4) << 2);
    #pragma unroll
    for (int n = 0; n < 7; ++n) {
        int cl = n * 16 + col;
        if (cl < 100) {
            #pragma unroll
            for (int r = 0; r < 4; ++r)
                Vb[(size_t)(re + r) * 100 + cl] = f2bf(acc[n][r]);
        }
    }
}

// ---------- segment softmax + weighted V reduce: ONE WAVE PER NODE ----------
__global__ __launch_bounds__(256) void k_soft(const float2* __restrict__ attn,
                                              const unsigned short* __restrict__ V,
                                              const int* __restrict__ off,
                                              float* __restrict__ agg) {
    const int lane = threadIdx.x & 63;
    const int n = blockIdx.x * 4 + (threadIdx.x >> 6);
    const int r0 = off[n], cnt = off[n + 1] - r0;
    float* __restrict__ aout = agg + (size_t)n * 100;
    if (cnt <= 0) {
        aout[lane] = 0.f;
        if (lane < 36) aout[64 + lane] = 0.f;
        return;
    }
    float m0 = -1e30f, m1 = -1e30f;
    for (int i = lane; i < cnt; i += 64) {
        float2 a = attn[r0 + i];
        m0 = fmaxf(m0, a.x); m1 = fmaxf(m1, a.y);
    }
    #pragma unroll
    for (int s = 1; s < 64; s <<= 1) {
        m0 = fmaxf(m0, __shfl_xor(m0, s));
        m1 = fmaxf(m1, __shfl_xor(m1, s));
    }
    float s0 = 0.f, s1 = 0.f;
    for (int i = lane; i < cnt; i += 64) {
        float2 a = attn[r0 + i];
        s0 += __expf(a.x - m0); s1 += __expf(a.y - m1);
    }
    #pragma unroll
    for (int s = 1; s < 64; s <<= 1) { s0 += __shfl_xor(s0, s); s1 += __shfl_xor(s1, s); }
    const float inv0 = 1.f / s0, inv1 = 1.f / s1;

    float acc_a = 0.f, acc_b = 0.f;
    for (int base = 0; base < cnt; base += 64) {
        int i = base + lane;
        float e0 = 0.f, e1 = 0.f;
        if (i < cnt) {
            float2 a = attn[r0 + i];
            e0 = __expf(a.x - m0) * inv0;
            e1 = __expf(a.y - m1) * inv1;
        }
        int lim = min(64, cnt - base);
        for (int j = 0; j < lim; ++j) {
            float p0 = __shfl(e0, j), p1 = __shfl(e1, j);
            const unsigned short* __restrict__ row = V + (size_t)(r0 + base + j) * 100;
            float pa = (lane < 50) ? p0 : p1;
            acc_a = fmaf(pa, bf2f(row[lane]), acc_a);
            if (lane < 36) acc_b = fmaf(p1, bf2f(row[64 + lane]), acc_b);
        }
    }
    aout[lane] = acc_a;
    if (lane < 36) aout[64 + lane] = acc_b;
}

// ---------- out proj + relu + layernorm: 4 nodes/block, wout row reused 4x ----------
__global__ __launch_bounds__(128) void k_out(const float* __restrict__ agg,
                                             const float* __restrict__ dst_h,
                                             const float* __restrict__ wout_w,
                                             const float* __restrict__ wout_b,
                                             const float* __restrict__ ln_g,
                                             const float* __restrict__ ln_b,
                                             float* __restrict__ out) {
    __shared__ float Fs[4][200];
    __shared__ float red[4][128];
    const int n0 = blockIdx.x * 4, t = threadIdx.x;
    for (int idx = t; idx < 800; idx += 128) {
        int n = idx / 200, i = idx % 200;
        Fs[n][i] = (i < 100) ? agg[(size_t)(n0 + n) * 100 + i]
                             : dst_h[(size_t)(n0 + n) * 100 + (i - 100)];
    }
    __syncthreads();
    float v[4] = {0.f, 0.f, 0.f, 0.f};
    if (t < 100) {
        float b = wout_b[t];
        v[0] = v[1] = v[2] = v[3] = b;
        const float* __restrict__ wr = wout_w + t * 200;
        for (int i = 0; i < 200; ++i) {
            float w = wr[i];
            #pragma unroll
            for (int n = 0; n < 4; ++n) v[n] = fmaf(Fs[n][i], w, v[n]);
        }
        #pragma unroll
        for (int n = 0; n < 4; ++n) v[n] = fmaxf(v[n], 0.f);
    }
    #pragma unroll
    for (int n = 0; n < 4; ++n) red[n][t] = (t < 100) ? v[n] : 0.f;
    __syncthreads();
    for (int s = 64; s > 0; s >>= 1) {
        if (t < s) {
            #pragma unroll
            for (int n = 0; n < 4; ++n) red[n][t] += red[n][t + s];
        }
        __syncthreads();
    }
    float mu[4];
    #pragma unroll
    for (int n = 0; n < 4; ++n) mu[n] = red[n][0] * 0.01f;
    __syncthreads();
    #pragma unroll
    for (int n = 0; n < 4; ++n) {
        float dv = (t < 100) ? (v[n] - mu[n]) : 0.f;
        red[n][t] = dv * dv;
    }
    __syncthreads();
    for (int s = 64; s > 0; s >>= 1) {
        if (t < s) {
            #pragma unroll
            for (int n = 0; n < 4; ++n) red[n][t] += red[n][t + s];
        }
        __syncthreads();
    }
    if (t < 100) {
        #pragma unroll
        for (int n = 0; n < 4; ++n) {
            float var = red[n][0] * 0.01f;
            out[(size_t)(n0 + n) * 100 + t] =
                (v[n] - mu[n]) * rsqrtf(var + LN_EPS) * ln_g[t] + ln_b[t];
        }
    }
}

extern "C" void kernel_launch(void* const* d_in, const int* in_sizes, int n_in,
                              void* d_out, int out_size, void* d_ws, size_t ws_size,
                              hipStream_t stream) {
    const float* dst_h   = (const float*)d_in[0];
    const float* src_h   = (const float*)d_in[1];
    const float* efeat   = (const float*)d_in[2];
    const float* td      = (const float*)d_in[3];
    const int*   edst    = (const int*)  d_in[4];
    const float* time_w  = (const float*)d_in[5];
    const float* time_b  = (const float*)d_in[6];
    const float* wq_w    = (const float*)d_in[7];
    const float* wq_b    = (const float*)d_in[8];
    const float* wkv_w   = (const float*)d_in[9];
    const float* wkv_b   = (const float*)d_in[10];
    const float* wout_w  = (const float*)d_in[11];
    const float* wout_b  = (const float*)d_in[12];
    const float* ln_g    = (const float*)d_in[13];
    const float* ln_b    = (const float*)d_in[14];
    float* out = (float*)d_out;

    char* ws = (char*)d_ws;
    size_t off = 0;
    auto carve = [&](size_t bytes) { char* p = ws + off; off = (off + bytes + 255) & ~(size_t)255; return p; };
    float*          QW   = (float*)carve((size_t)N_DST * 600 * 4);
    float2*         attn = (float2*)carve((size_t)N_EDGE * 2 * 4);
    unsigned short* Vb   = (unsigned short*)carve((size_t)N_EDGE * 100 * 2);
    float*          agg  = (float*)carve((size_t)N_DST * 100 * 4);
    unsigned short* Wvp  = (unsigned short*)carve(35840 * 2);
    float*          zq   = (float*)carve(100 * 4);
    float*          A    = (float*)carve(60000 * 4);
    float*          C    = (float*)carve(600 * 4);
    int*            offs = (int*)carve((size_t)(N_DST + 1) * 4);

    k_prep<<<(35940 + 255) / 256, 256, 0, stream>>>(wkv_w, wq_w, wq_b, time_b, Wvp, zq);
    k_precomp<<<(60600 + 255) / 256, 256, 0, stream>>>(wq_w, wkv_w, zq, A, C);
    k_offsets<<<(N_DST + 1 + 255) / 256, 256, 0, stream>>>(edst, offs);
    k_qw<<<N_DST / 16, 256, 0, stream>>>(dst_h, A, C, QW);
    k_edge<<<N_EDGE / 64, 256, 0, stream>>>(src_h, efeat, td, edst, time_w, time_b,
                                            Wvp, wkv_b, QW, Vb, attn);
    k_soft<<<N_DST / 4, 256, 0, stream>>>(attn, Vb, offs, agg);
    k_out<<<N_DST / 4, 128, 0, stream>>>(agg, dst_h, wout_w, wout_b, ln_g, ln_b, out);
}

// Round 4
// 574.588 us; speedup vs baseline: 2.7145x; 1.5917x over previous
//
#include <hip/hip_runtime.h>
#include <math.h>

#define N_DST   32768
#define N_EDGE  524288
#define LN_EPS  1e-5f

typedef __attribute__((ext_vector_type(8))) short short8b;   // 8 bf16 (4 VGPR)
typedef __attribute__((ext_vector_type(4))) short short4b;   // 4 bf16 (8 B)
typedef __attribute__((ext_vector_type(4))) float f32x4;

static __device__ __forceinline__ unsigned short f2bf(float f) {
    unsigned u = __float_as_uint(f);
    u += 0x7fff + ((u >> 16) & 1);          // round-to-nearest-even
    return (unsigned short)(u >> 16);
}
static __device__ __forceinline__ float bf2f(unsigned short s) {
    return __uint_as_float(((unsigned)s) << 16);
}

// ---------- prep: pack V-weights into MFMA B-fragment order (bf16), fold zq ----------
// Wvp flat index: ((kc*7 + n)*64 + lane)*8 + jj ; value = wkv_w[100 + n*16+(lane&15)][kc*32 + (lane>>4)*8 + jj]
__global__ void k_prep(const float* __restrict__ wkv_w, const float* __restrict__ wq_w,
                       const float* __restrict__ wq_b, const float* __restrict__ time_b,
                       unsigned short* __restrict__ Wvp, float* __restrict__ zq) {
    int idx = blockIdx.x * 256 + threadIdx.x;
    if (idx < 35840) {
        int jj = idx & 7, l = (idx >> 3) & 63, n = (idx >> 9) % 7, kc = idx / 3584;
        int c = n * 16 + (l & 15);
        int k = kc * 32 + ((l >> 4) << 3) + jj;
        float v = (c < 100 && k < 300) ? wkv_w[(size_t)(100 + c) * 300 + k] : 0.f;
        Wvp[idx] = f2bf(v);
    } else if (idx < 35940) {
        int o = idx - 35840;
        float acc = wq_b[o];
        for (int j = 0; j < 100; ++j)
            acc += cosf(time_b[j]) * wq_w[o * 200 + 100 + j];
        zq[o] = acc;
    }
}

// ---------- A[i][j] = sum_d wq_w[h*50+d][i] * wkv_w[h*50+d][j%300]  (j = h*300+kk) ----------
// C[j]    = sum_d zq[h*50+d] * wkv_w[h*50+d][kk]
__global__ void k_precomp(const float* __restrict__ wq_w, const float* __restrict__ wkv_w,
                          const float* __restrict__ zq,
                          float* __restrict__ A, float* __restrict__ C) {
    int idx = blockIdx.x * 256 + threadIdx.x;
    if (idx < 60000) {
        int i = idx / 600, j = idx % 600;
        int h = j / 300, kk = j % 300;
        const float* __restrict__ wq = wq_w + (size_t)(h * 50) * 200 + i;
        const float* __restrict__ wk = wkv_w + (size_t)(h * 50) * 300 + kk;
        float acc = 0.f;
        #pragma unroll 10
        for (int d = 0; d < 50; ++d) acc = fmaf(wq[(size_t)d * 200], wk[(size_t)d * 300], acc);
        A[idx] = acc;
    } else if (idx < 60600) {
        int j = idx - 60000;
        int h = j / 300, kk = j % 300;
        float acc = 0.f;
        for (int d = 0; d < 50; ++d)
            acc = fmaf(zq[h * 50 + d], wkv_w[(size_t)(h * 50 + d) * 300 + kk], acc);
        C[j] = acc;
    }
}

// ---------- CSR offsets via binary search over sorted edge_dst ----------
__global__ void k_offsets(const int* __restrict__ dst, int* __restrict__ off) {
    int n = blockIdx.x * 256 + threadIdx.x;
    if (n > N_DST) return;
    int lo = 0, hi = N_EDGE;
    while (lo < hi) {
        int mid = (lo + hi) >> 1;
        if (dst[mid] < n) lo = mid + 1; else hi = mid;
    }
    off[n] = lo;
}

// ---------- QW = dst_h @ A + C : [32768 x 100] x [100 x 600] ----------
__global__ __launch_bounds__(256) void k_qw(const float* __restrict__ dst_h,
                                            const float* __restrict__ A,
                                            const float* __restrict__ C,
                                            float* __restrict__ QW) {
    __shared__ float Ds[16][100];
    int n0 = blockIdx.x * 16, t = threadIdx.x;
    for (int idx = t; idx < 1600; idx += 256)
        Ds[idx / 100][idx % 100] = dst_h[(size_t)n0 * 100 + idx];
    __syncthreads();
    for (int pass = 0; pass < 3; ++pass) {
        int c = pass * 256 + t;
        if (c >= 600) break;
        float cb = C[c];
        float acc[16];
        #pragma unroll
        for (int n = 0; n < 16; ++n) acc[n] = cb;
        for (int k = 0; k < 100; ++k) {
            float a = A[(size_t)k * 600 + c];
            #pragma unroll
            for (int n = 0; n < 16; ++n) acc[n] = fmaf(Ds[n][k], a, acc[n]);
        }
        #pragma unroll
        for (int n = 0; n < 16; ++n) QW[(size_t)(n0 + n) * 600 + c] = acc[n];
    }
}

// ---------- edge kernel: fused staging + fp32 logits + bf16 MFMA V-GEMM ----------
// 64 edges/block, 256 thr (4 waves). X in LDS bf16 [64][320], XOR-swizzled.
// __launch_bounds__(256,2): allow >=128 VGPRs so acc[7]+w[7] stay in registers
// (with (256,4) the allocator capped at 64 VGPRs and spilled -> 1.2 GB scratch
//  writes/dispatch, occupancy 3.5%).
__global__ __launch_bounds__(256, 2) void k_edge(
        const float* __restrict__ src_h, const float* __restrict__ efeat,
        const float* __restrict__ td,    const int* __restrict__ edge_dst,
        const float* __restrict__ time_w, const float* __restrict__ time_b,
        const unsigned short* __restrict__ Wvp, const float* __restrict__ wkv_b,
        const float* __restrict__ QW,
        unsigned short* __restrict__ Vb, float2* __restrict__ attn) {
    __shared__ alignas(16) char Xs[64 * 640];   // 40 KiB: bf16 [64][320], byte(row,k)=(row*640+2k)^((row&7)<<4)
    const int t = threadIdx.x;
    const int e0 = blockIdx.x * 64;
    const int lane = t & 63;

    // ---- staging + fp32 logits: 4 threads per edge ----
    {
        const int e = t >> 2, s = t & 3;
        const int eg = e0 + e;
        const int dst = edge_dst[eg];
        const float tdv = td[eg];
        const float* __restrict__ qwb = QW + (size_t)dst * 600;
        const float4* __restrict__ s4 = (const float4*)(src_h + (size_t)eg * 100);
        const float4* __restrict__ f4 = (const float4*)(efeat + (size_t)eg * 100);
        float p0 = 0.f, p1 = 0.f;
        #pragma unroll
        for (int j = 0; j < 20; ++j) {
            int q = s + 4 * j;                       // q in [0,80): k = 4q
            float4 x = make_float4(0.f, 0.f, 0.f, 0.f);
            if (q < 25) {
                x = s4[q];
            } else if (q < 50) {
                x = f4[q - 25];
            } else if (q < 75) {
                float4 tw = ((const float4*)time_w)[q - 50];
                float4 tb = ((const float4*)time_b)[q - 50];
                x.x = cosf(fmaf(tdv, tw.x, tb.x));
                x.y = cosf(fmaf(tdv, tw.y, tb.y));
                x.z = cosf(fmaf(tdv, tw.z, tb.z));
                x.w = cosf(fmaf(tdv, tw.w, tb.w));
            }
            if (q < 75) {
                float4 a0 = ((const float4*)qwb)[q];
                float4 a1 = ((const float4*)(qwb + 300))[q];
                p0 = fmaf(x.x, a0.x, fmaf(x.y, a0.y, fmaf(x.z, a0.z, fmaf(x.w, a0.w, p0))));
                p1 = fmaf(x.x, a1.x, fmaf(x.y, a1.y, fmaf(x.z, a1.z, fmaf(x.w, a1.w, p1))));
            }
            short4b pk;
            pk[0] = (short)f2bf(x.x); pk[1] = (short)f2bf(x.y);
            pk[2] = (short)f2bf(x.z); pk[3] = (short)f2bf(x.w);
            int wb = (e * 640 + q * 8) ^ ((e & 7) << 4);
            *(short4b*)(&Xs[wb]) = pk;
        }
        p0 += __shfl_xor(p0, 1); p0 += __shfl_xor(p0, 2);
        p1 += __shfl_xor(p1, 1); p1 += __shfl_xor(p1, 2);
        if (s == 0) {
            float l0 = p0 > 0.f ? p0 : 0.2f * p0;
            float l1 = p1 > 0.f ? p1 : 0.2f * p1;
            attn[eg] = make_float2(l0, l1);
        }
    }
    __syncthreads();

    // ---- MFMA V-GEMM: wave wv owns Mfrag wv (16 edges) x 7 Nfrags ----
    const int wv = t >> 6;
    const int col = lane & 15;
    const int arow = wv * 16 + col;
    const int abase = arow * 640 + ((lane >> 4) << 4);
    const int aswz = (arow & 7) << 4;
    const short8b* __restrict__ Wv8 = (const short8b*)Wvp;

    f32x4 acc[7];
    #pragma unroll
    for (int n = 0; n < 7; ++n) {
        int cl = n * 16 + col;
        float b = (cl < 100) ? wkv_b[100 + cl] : 0.f;
        acc[n] = (f32x4){b, b, b, b};
    }
    #pragma unroll
    for (int kc = 0; kc < 10; ++kc) {
        short8b a = *(const short8b*)(&Xs[(abase + kc * 64) ^ aswz]);
        short8b w[7];
        #pragma unroll
        for (int n = 0; n < 7; ++n)
            w[n] = Wv8[(kc * 7 + n) * 64 + lane];
        #pragma unroll
        for (int n = 0; n < 7; ++n)
            acc[n] = __builtin_amdgcn_mfma_f32_16x16x32_bf16(a, w[n], acc[n], 0, 0, 0);
    }
    // V writeout (bf16): C/D layout col=lane&15, row=(lane>>4)*4+r  [m89-verified]
    const int re = e0 + wv * 16 + ((lane >> 4) << 2);
    #pragma unroll
    for (int n = 0; n < 7; ++n) {
        int cl = n * 16 + col;
        if (cl < 100) {
            #pragma unroll
            for (int r = 0; r < 4; ++r)
                Vb[(size_t)(re + r) * 100 + cl] = f2bf(acc[n][r]);
        }
    }
}

// ---------- segment softmax + weighted V reduce: ONE WAVE PER NODE ----------
__global__ __launch_bounds__(256) void k_soft(const float2* __restrict__ attn,
                                              const unsigned short* __restrict__ V,
                                              const int* __restrict__ off,
                                              float* __restrict__ agg) {
    const int lane = threadIdx.x & 63;
    const int n = blockIdx.x * 4 + (threadIdx.x >> 6);
    const int r0 = off[n], cnt = off[n + 1] - r0;
    float* __restrict__ aout = agg + (size_t)n * 100;
    if (cnt <= 0) {
        aout[lane] = 0.f;
        if (lane < 36) aout[64 + lane] = 0.f;
        return;
    }
    float m0 = -1e30f, m1 = -1e30f;
    for (int i = lane; i < cnt; i += 64) {
        float2 a = attn[r0 + i];
        m0 = fmaxf(m0, a.x); m1 = fmaxf(m1, a.y);
    }
    #pragma unroll
    for (int s = 1; s < 64; s <<= 1) {
        m0 = fmaxf(m0, __shfl_xor(m0, s));
        m1 = fmaxf(m1, __shfl_xor(m1, s));
    }
    float s0 = 0.f, s1 = 0.f;
    for (int i = lane; i < cnt; i += 64) {
        float2 a = attn[r0 + i];
        s0 += __expf(a.x - m0); s1 += __expf(a.y - m1);
    }
    #pragma unroll
    for (int s = 1; s < 64; s <<= 1) { s0 += __shfl_xor(s0, s); s1 += __shfl_xor(s1, s); }
    const float inv0 = 1.f / s0, inv1 = 1.f / s1;

    float acc_a = 0.f, acc_b = 0.f;
    for (int base = 0; base < cnt; base += 64) {
        int i = base + lane;
        float e0 = 0.f, e1 = 0.f;
        if (i < cnt) {
            float2 a = attn[r0 + i];
            e0 = __expf(a.x - m0) * inv0;
            e1 = __expf(a.y - m1) * inv1;
        }
        int lim = min(64, cnt - base);
        for (int j = 0; j < lim; ++j) {
            float p0 = __shfl(e0, j), p1 = __shfl(e1, j);
            const unsigned short* __restrict__ row = V + (size_t)(r0 + base + j) * 100;
            float pa = (lane < 50) ? p0 : p1;
            acc_a = fmaf(pa, bf2f(row[lane]), acc_a);
            if (lane < 36) acc_b = fmaf(p1, bf2f(row[64 + lane]), acc_b);
        }
    }
    aout[lane] = acc_a;
    if (lane < 36) aout[64 + lane] = acc_b;
}

// ---------- out proj + relu + layernorm: 4 nodes/block, wout row reused 4x ----------
__global__ __launch_bounds__(128) void k_out(const float* __restrict__ agg,
                                             const float* __restrict__ dst_h,
                                             const float* __restrict__ wout_w,
                                             const float* __restrict__ wout_b,
                                             const float* __restrict__ ln_g,
                                             const float* __restrict__ ln_b,
                                             float* __restrict__ out) {
    __shared__ float Fs[4][200];
    __shared__ float red[4][128];
    const int n0 = blockIdx.x * 4, t = threadIdx.x;
    for (int idx = t; idx < 800; idx += 128) {
        int n = idx / 200, i = idx % 200;
        Fs[n][i] = (i < 100) ? agg[(size_t)(n0 + n) * 100 + i]
                             : dst_h[(size_t)(n0 + n) * 100 + (i - 100)];
    }
    __syncthreads();
    float v[4] = {0.f, 0.f, 0.f, 0.f};
    if (t < 100) {
        float b = wout_b[t];
        v[0] = v[1] = v[2] = v[3] = b;
        const float* __restrict__ wr = wout_w + t * 200;
        for (int i = 0; i < 200; ++i) {
            float w = wr[i];
            #pragma unroll
            for (int n = 0; n < 4; ++n) v[n] = fmaf(Fs[n][i], w, v[n]);
        }
        #pragma unroll
        for (int n = 0; n < 4; ++n) v[n] = fmaxf(v[n], 0.f);
    }
    #pragma unroll
    for (int n = 0; n < 4; ++n) red[n][t] = (t < 100) ? v[n] : 0.f;
    __syncthreads();
    for (int s = 64; s > 0; s >>= 1) {
        if (t < s) {
            #pragma unroll
            for (int n = 0; n < 4; ++n) red[n][t] += red[n][t + s];
        }
        __syncthreads();
    }
    float mu[4];
    #pragma unroll
    for (int n = 0; n < 4; ++n) mu[n] = red[n][0] * 0.01f;
    __syncthreads();
    #pragma unroll
    for (int n = 0; n < 4; ++n) {
        float dv = (t < 100) ? (v[n] - mu[n]) : 0.f;
        red[n][t] = dv * dv;
    }
    __syncthreads();
    for (int s = 64; s > 0; s >>= 1) {
        if (t < s) {
            #pragma unroll
            for (int n = 0; n < 4; ++n) red[n][t] += red[n][t + s];
        }
        __syncthreads();
    }
    if (t < 100) {
        #pragma unroll
        for (int n = 0; n < 4; ++n) {
            float var = red[n][0] * 0.01f;
            out[(size_t)(n0 + n) * 100 + t] =
                (v[n] - mu[n]) * rsqrtf(var + LN_EPS) * ln_g[t] + ln_b[t];
        }
    }
}

extern "C" void kernel_launch(void* const* d_in, const int* in_sizes, int n_in,
                              void* d_out, int out_size, void* d_ws, size_t ws_size,
                              hipStream_t stream) {
    const float* dst_h   = (const float*)d_in[0];
    const float* src_h   = (const float*)d_in[1];
    const float* efeat   = (const float*)d_in[2];
    const float* td      = (const float*)d_in[3];
    const int*   edst    = (const int*)  d_in[4];
    const float* time_w  = (const float*)d_in[5];
    const float* time_b  = (const float*)d_in[6];
    const float* wq_w    = (const float*)d_in[7];
    const float* wq_b    = (const float*)d_in[8];
    const float* wkv_w   = (const float*)d_in[9];
    const float* wkv_b   = (const float*)d_in[10];
    const float* wout_w  = (const float*)d_in[11];
    const float* wout_b  = (const float*)d_in[12];
    const float* ln_g    = (const float*)d_in[13];
    const float* ln_b    = (const float*)d_in[14];
    float* out = (float*)d_out;

    char* ws = (char*)d_ws;
    size_t off = 0;
    auto carve = [&](size_t bytes) { char* p = ws + off; off = (off + bytes + 255) & ~(size_t)255; return p; };
    float*          QW   = (float*)carve((size_t)N_DST * 600 * 4);
    float2*         attn = (float2*)carve((size_t)N_EDGE * 2 * 4);
    unsigned short* Vb   = (unsigned short*)carve((size_t)N_EDGE * 100 * 2);
    float*          agg  = (float*)carve((size_t)N_DST * 100 * 4);
    unsigned short* Wvp  = (unsigned short*)carve(35840 * 2);
    float*          zq   = (float*)carve(100 * 4);
    float*          A    = (float*)carve(60000 * 4);
    float*          C    = (float*)carve(600 * 4);
    int*            offs = (int*)carve((size_t)(N_DST + 1) * 4);

    k_prep<<<(35940 + 255) / 256, 256, 0, stream>>>(wkv_w, wq_w, wq_b, time_b, Wvp, zq);
    k_precomp<<<(60600 + 255) / 256, 256, 0, stream>>>(wq_w, wkv_w, zq, A, C);
    k_offsets<<<(N_DST + 1 + 255) / 256, 256, 0, stream>>>(edst, offs);
    k_qw<<<N_DST / 16, 256, 0, stream>>>(dst_h, A, C, QW);
    k_edge<<<N_EDGE / 64, 256, 0, stream>>>(src_h, efeat, td, edst, time_w, time_b,
                                            Wvp, wkv_b, QW, Vb, attn);
    k_soft<<<N_DST / 4, 256, 0, stream>>>(attn, Vb, offs, agg);
    k_out<<<N_DST / 4, 128, 0, stream>>>(agg, dst_h, wout_w, wout_b, ln_g, ln_b, out);
}